// Round 10
// baseline (122.873 us; speedup 1.0000x reference)
//
#include <hip/hip_runtime.h>

#define SQ 2048
#define DM 1024
#define NH 16
#define HD 64

typedef __bf16 bf16x8 __attribute__((ext_vector_type(8)));
typedef float f32x4 __attribute__((ext_vector_type(4)));
typedef unsigned short u16;
typedef unsigned int u32;

// fp32 -> bf16 round-to-nearest-even (bulk convert pass)
__device__ __forceinline__ u16 f2b(float f) {
  union { float f; u32 u; } c; c.f = f;
  return (u16)((c.u + 0x7FFFu + ((c.u >> 16) & 1u)) >> 16);
}

// async global->LDS, 16B per lane; lds dest = wave-uniform base + lane*16
__device__ __forceinline__ void gll16(const void* g, void* l) {
  __builtin_amdgcn_global_load_lds(
      (const __attribute__((address_space(1))) void*)g,
      (__attribute__((address_space(3))) void*)l, 16, 0, 0);
}

// ---------------------------------------------------------------------------
// fp32 -> bf16 convert pass: X (4M elems) + Wq/Wk/Wv/Wo (1M each)
// Wq/Wk/Wv land contiguous -> usable as one 3072x1024 matrix.
// ---------------------------------------------------------------------------
__global__ void __launch_bounds__(256) conv_bf16(
    const float* __restrict__ X,
    const float* __restrict__ Wq, const float* __restrict__ Wk,
    const float* __restrict__ Wv, const float* __restrict__ Wo,
    u16* __restrict__ Xb, u16* __restrict__ Wqb, u16* __restrict__ Wkb,
    u16* __restrict__ Wvb, u16* __restrict__ Wob) {
  const size_t e = ((size_t)blockIdx.x * 256 + threadIdx.x) * 8;
  const float* src; u16* dst; size_t rel;
  if (e < 4194304u)      { src = X;  dst = Xb;  rel = e; }
  else if (e < 5242880u) { src = Wq; dst = Wqb; rel = e - 4194304u; }
  else if (e < 6291456u) { src = Wk; dst = Wkb; rel = e - 5242880u; }
  else if (e < 7340032u) { src = Wv; dst = Wvb; rel = e - 6291456u; }
  else                   { src = Wo; dst = Wob; rel = e - 7340032u; }
  float4 a = *(const float4*)(src + rel);
  float4 b = *(const float4*)(src + rel + 4);
  union { u16 h[8]; uint4 v; } o;
  o.h[0] = f2b(a.x); o.h[1] = f2b(a.y); o.h[2] = f2b(a.z); o.h[3] = f2b(a.w);
  o.h[4] = f2b(b.x); o.h[5] = f2b(b.y); o.h[6] = f2b(b.z); o.h[7] = f2b(b.w);
  *(uint4*)(dst + rel) = o.v;
}

// ---------------------------------------------------------------------------
// m97-style 128x128 NT GEMM core, bf16 inputs, BK=32, global_load_lds staging,
// double-buffered LDS ([2][128][32] linear per operand), 2-phase schedule.
// ---------------------------------------------------------------------------
__device__ __forceinline__ void stage128(const u16* __restrict__ A, const u16* __restrict__ B,
                                         u16* sA, u16* sB, int m0, int n0, int kt,
                                         int w, int l) {
#pragma unroll
  for (int c = 0; c < 2; ++c) {
    const int g = w * 2 + c;       // chunk-group 0..7 (1 KB each)
    const int s = g * 64 + l;      // 16B slot 0..511
    const int r = s >> 2, cc = s & 3;
    gll16(A + (size_t)(m0 + r) * DM + kt * 32 + cc * 8, sA + g * 512);
    gll16(B + (size_t)(n0 + r) * DM + kt * 32 + cc * 8, sB + g * 512);
  }
}

__device__ __forceinline__ void gemm_core2(const u16* __restrict__ A, const u16* __restrict__ B,
                                           u16* sA, u16* sB,   // each [2][4096] u16
                                           int m0, int n0, f32x4 acc[4][4]) {
  const int t = threadIdx.x, l = t & 63, w = t >> 6;
  const int wr = w >> 1, wc = w & 1, lg = l >> 4, li = l & 15;

  stage128(A, B, sA, sB, m0, n0, 0, w, l);
  __syncthreads();  // drains vmcnt(0) before barrier
  int cur = 0;
  for (int kt = 0; kt < DM / 32; ++kt) {
    if (kt + 1 < DM / 32)
      stage128(A, B, sA + (cur ^ 1) * 4096, sB + (cur ^ 1) * 4096, m0, n0, kt + 1, w, l);
    bf16x8 aF[4], bF[4];
#pragma unroll
    for (int mi = 0; mi < 4; ++mi)
      aF[mi] = *(const bf16x8*)(sA + cur * 4096 + (wr * 64 + mi * 16 + li) * 32 + lg * 8);
#pragma unroll
    for (int ni = 0; ni < 4; ++ni)
      bF[ni] = *(const bf16x8*)(sB + cur * 4096 + (wc * 64 + ni * 16 + li) * 32 + lg * 8);
#pragma unroll
    for (int mi = 0; mi < 4; ++mi)
#pragma unroll
      for (int ni = 0; ni < 4; ++ni)
        acc[mi][ni] = __builtin_amdgcn_mfma_f32_16x16x32_bf16(aF[mi], bF[ni], acc[mi][ni], 0, 0, 0);
    __syncthreads();
    cur ^= 1;
  }
}

// ---------------------------------------------------------------------------
// Merged QKV projection: one 4096x3072x1024 GEMM (Wqkv contiguous bf16).
// n in [0,1024): Q (scaled log2e/8); [1024,2048): K; [2048,3072): V^T.
// Grid (24,32) x-fastest: mode-interleaved dispatch + shared A-panel in L2.
// ---------------------------------------------------------------------------
__global__ void __launch_bounds__(256) qkv_gemm(
    const u16* __restrict__ Xb, const u16* __restrict__ Wqkv,
    const float* __restrict__ bq, const float* __restrict__ bk, const float* __restrict__ bv,
    u16* __restrict__ Qb, u16* __restrict__ Kb, u16* __restrict__ Vt) {
  __shared__ u16 sA[8192];
  __shared__ u16 sB[8192];
  const int m0 = blockIdx.y * 128, n0 = blockIdx.x * 128;
  const int mode = n0 >> 10;              // 0:Q 1:K 2:V (block-uniform)
  const float* bias = (mode == 0) ? bq : (mode == 1) ? bk : bv;

  f32x4 acc[4][4];
  f32x4 z4 = {0.f, 0.f, 0.f, 0.f};
#pragma unroll
  for (int i = 0; i < 4; ++i)
#pragma unroll
    for (int j = 0; j < 4; ++j) acc[i][j] = z4;

  gemm_core2(Xb, Wqkv, sA, sB, m0, n0, acc);

  const int t = threadIdx.x;
  const int l = t & 63, w = t >> 6;
  const int wr = w >> 1, wc = w & 1, lg = l >> 4, li = l & 15;
#pragma unroll
  for (int mi = 0; mi < 4; ++mi) {
    const int m = m0 + wr * 64 + mi * 16 + lg * 4;
    const int b = m >> 11;           // batch
    const int s = m & 2047;          // seq pos
#pragma unroll
    for (int ni = 0; ni < 4; ++ni) {
      const int n = n0 + wc * 64 + ni * 16 + li;
      const int nn = n - (mode << 10);     // local col 0..1023
      const int h = nn >> 6, dd = nn & 63;
      const float bia = bias[nn];
      const size_t bh = (size_t)(b * NH + h);
      if (mode == 2) {
        // V^T: 4 consecutive seq positions for fixed dd -> one 8B store
        union { u16 h4[4]; uint2 u; } pk;
#pragma unroll
        for (int r = 0; r < 4; ++r) pk.h4[r] = f2b(acc[mi][ni][r] + bia);
        *(uint2*)(Vt + (bh * HD + dd) * SQ + s) = pk.u;
      } else {
#pragma unroll
        for (int r = 0; r < 4; ++r) {
          const float val = acc[mi][ni][r] + bia;
          const int ss = s + r;
          // Q prescale: (1/sqrt(HD)) * log2(e) so attn works in exp2 domain
          if (mode == 0) Qb[(bh * SQ + ss) * HD + dd] = f2b(val * 0.180336880f);
          else           Kb[(bh * SQ + ss) * HD + dd] = f2b(val);
        }
      }
    }
  }
}

// ---------------------------------------------------------------------------
// Final projection: out = Ao * Wo^T + bo (bf16 in, fp32 out).
// 64x128 tile, grid (8,64) = 512 blocks = 2 blocks/CU.
// ---------------------------------------------------------------------------
__global__ void __launch_bounds__(256) out_gemm(
    const u16* __restrict__ Ag, const u16* __restrict__ Wob,
    const float* __restrict__ bo, float* __restrict__ out) {
  __shared__ u16 sA[2][2048];   // [64][32] u16 per buf (4KB)
  __shared__ u16 sB[2][4096];   // [128][32] u16 per buf (8KB)
  const int t = threadIdx.x, l = t & 63, w = t >> 6;
  const int wr = w >> 1, wc = w & 1, lg = l >> 4, li = l & 15;
  const int m0 = blockIdx.y * 64, n0 = blockIdx.x * 128;

  auto stage = [&](int buf, int kt) {
    {
      const int s = w * 64 + l;          // A slot 0..255
      const int r = s >> 2, cc = s & 3;
      gll16(Ag + (size_t)(m0 + r) * DM + kt * 32 + cc * 8, &sA[buf][w * 512]);
    }
#pragma unroll
    for (int c = 0; c < 2; ++c) {
      const int g = w * 2 + c;           // B chunk 0..7
      const int s = g * 64 + l;          // B slot 0..511
      const int r = s >> 2, cc = s & 3;
      gll16(Wob + (size_t)(n0 + r) * DM + kt * 32 + cc * 8, &sB[buf][g * 512]);
    }
  };

  f32x4 acc[2][4];
  f32x4 z4 = {0.f, 0.f, 0.f, 0.f};
#pragma unroll
  for (int i = 0; i < 2; ++i)
#pragma unroll
    for (int j = 0; j < 4; ++j) acc[i][j] = z4;

  stage(0, 0);
  __syncthreads();
  int cur = 0;
  for (int kt = 0; kt < DM / 32; ++kt) {
    if (kt + 1 < DM / 32) stage(cur ^ 1, kt + 1);
    bf16x8 aF[2], bF[4];
#pragma unroll
    for (int mi = 0; mi < 2; ++mi)
      aF[mi] = *(const bf16x8*)(&sA[cur][(wr * 32 + mi * 16 + li) * 32 + lg * 8]);
#pragma unroll
    for (int ni = 0; ni < 4; ++ni)
      bF[ni] = *(const bf16x8*)(&sB[cur][(wc * 64 + ni * 16 + li) * 32 + lg * 8]);
#pragma unroll
    for (int mi = 0; mi < 2; ++mi)
#pragma unroll
      for (int ni = 0; ni < 4; ++ni)
        acc[mi][ni] = __builtin_amdgcn_mfma_f32_16x16x32_bf16(aF[mi], bF[ni], acc[mi][ni], 0, 0, 0);
    __syncthreads();
    cur ^= 1;
  }

#pragma unroll
  for (int mi = 0; mi < 2; ++mi) {
    const int m = m0 + wr * 32 + mi * 16 + lg * 4;
#pragma unroll
    for (int ni = 0; ni < 4; ++ni) {
      const int n = n0 + wc * 64 + ni * 16 + li;
      const float bia = bo[n];
#pragma unroll
      for (int r = 0; r < 4; ++r)
        out[(size_t)(m + r) * DM + n] = acc[mi][ni][r] + bia;
    }
  }
}

// ---------------------------------------------------------------------------
// Flash attention v9 = v8 pipeline at 16 q/wave (occupancy fix, V kept in LDS):
//  - 4 waves x 16 queries, grid (32 bh, 32 qt) = 1024 blocks = 4 blocks/CU
//    = 16 waves/CU (v8 was 8): 4 waves/SIMD interleave QK/exp2/PV chains
//  - K sigma-staged + V^T staged, both gll16 dbuf (tile-ahead prefetch)
//  - zero-shuffle P->PV; fixed-anchor exp2 softmax; masked queries via qf=0
//  - l via ones-MFMA; bh-fastest grid pins 4 heads' K/V per XCD L2
// ---------------------------------------------------------------------------
__global__ void __launch_bounds__(256) attn_v9(
    const u16* __restrict__ Qb, const u16* __restrict__ Kb, const u16* __restrict__ Vt,
    const int* __restrict__ vlen, u16* __restrict__ Ao) {
  __shared__ u16 sK[2][4096];   // [64 keys(sigma)][64 dk], chunk-XOR swizzled
  __shared__ u16 sV[2][4096];   // [64 d][64 keys(natural)], chunk-XOR swizzled
  const int bh = blockIdx.x, qt = blockIdx.y;
  const int t = threadIdx.x, w = t >> 6, l = t & 63, lg = l >> 4, li = l & 15;
  const int vl = vlen[bh];
  const u16* Qh = Qb + (size_t)bh * SQ * HD;
  const u16* Kh = Kb + (size_t)bh * SQ * HD;
  const u16* Vh = Vt + (size_t)bh * HD * SQ;
  const int q0 = qt * 64 + w * 16;        // this wave's 16 queries: q0 + li

  // Q fragment, masked queries zeroed (uniform softmax == reference row-mask)
  const bool mq = (q0 + li) >= vl;
  bf16x8 qf[2];
#pragma unroll
  for (int kk = 0; kk < 2; ++kk) {
    qf[kk] = *(const bf16x8*)(Qh + (size_t)(q0 + li) * HD + kk * 32 + lg * 8);
    if (mq) {
      union { u32 u[4]; bf16x8 v; } z; z.u[0] = z.u[1] = z.u[2] = z.u[3] = 0;
      qf[kk] = z.v;
    }
  }

  // ones A-fragment (for l = ones * P MFMA)
  union { u16 h[8]; bf16x8 v; } onesU;
#pragma unroll
  for (int j = 0; j < 8; ++j) onesU.h[j] = 0x3F80;  // bf16 1.0
  const bf16x8 ones = onesU.v;

  // staging geometry: 8 x 1KB chunks per operand, 2 per wave; K gets sigma row
  // permute, both get chunk-XOR swizzle folded into the per-lane GLOBAL source
  int gq[2]; int kOff[2], vOff[2];
#pragma unroll
  for (int c = 0; c < 2; ++c) {
    gq[c] = w * 2 + c;
    const int s = gq[c] * 64 + l;      // 16B slot 0..511
    const int r = s >> 3, cs = s & 7;
    const int csrc = cs ^ (r & 7);
    const int sig = (r & 32) | (((r >> 2) & 3) << 3) | (((r >> 4) & 1) << 2) | (r & 3);
    kOff[c] = sig * HD + csrc * 8;
    vOff[c] = r * SQ + csrc * 8;
  }
  auto stageKV = [&](int buf, int kt) {
#pragma unroll
    for (int c = 0; c < 2; ++c) {
      gll16(Kh + (size_t)(kt * 64) * HD + kOff[c], &sK[buf][gq[c] * 512]);
      gll16(Vh + (size_t)(kt * 64) + vOff[c], &sV[buf][gq[c] * 512]);
    }
  };

  f32x4 z4 = {0.f, 0.f, 0.f, 0.f};
  f32x4 acc[4], lacc;
#pragma unroll
  for (int ni = 0; ni < 4; ++ni) acc[ni] = z4;
  lacc = z4;

  stageKV(0, 0);
  __syncthreads();
  int cur = 0;
  for (int kt = 0; kt < SQ / 64; ++kt) {
    if (kt + 1 < SQ / 64) stageKV(cur ^ 1, kt + 1);

    // S^T = K Q^T (log2 domain)
    f32x4 sc[4];
#pragma unroll
    for (int ni = 0; ni < 4; ++ni) {
      const int row = ni * 16 + li;
      bf16x8 kf0 = *(const bf16x8*)(&sK[cur][row * 64 + ((lg ^ (row & 7)) * 8)]);
      bf16x8 kf1 = *(const bf16x8*)(&sK[cur][row * 64 + (((4 + lg) ^ (row & 7)) * 8)]);
      sc[ni] = __builtin_amdgcn_mfma_f32_16x16x32_bf16(kf0, qf[0], z4, 0, 0, 0);
      sc[ni] = __builtin_amdgcn_mfma_f32_16x16x32_bf16(kf1, qf[1], sc[ni], 0, 0, 0);
    }

    // fixed-anchor softmax: p = exp2(sc), packed straight into PV B-frags
    bf16x8 pb[2];
#pragma unroll
    for (int h = 0; h < 2; ++h) {
      union { __bf16 e[8]; bf16x8 v; } P;
#pragma unroll
      for (int j = 0; j < 4; ++j) {
        P.e[j]     = (__bf16)__builtin_amdgcn_exp2f(sc[2 * h][j]);
        P.e[4 + j] = (__bf16)__builtin_amdgcn_exp2f(sc[2 * h + 1][j]);
      }
      pb[h] = P.v;
    }

    // l += ones * P (matrix pipe; every lane gets its query's l in all 4 regs)
    lacc = __builtin_amdgcn_mfma_f32_16x16x32_bf16(ones, pb[0], lacc, 0, 0, 0);
    lacc = __builtin_amdgcn_mfma_f32_16x16x32_bf16(ones, pb[1], lacc, 0, 0, 0);

    // O^T += V^T P^T (V from LDS, staged last tile -> no same-tile stall)
#pragma unroll
    for (int ni = 0; ni < 4; ++ni) {
      const int row = ni * 16 + li;
      bf16x8 vf0 = *(const bf16x8*)(&sV[cur][row * 64 + ((lg ^ (row & 7)) * 8)]);
      bf16x8 vf1 = *(const bf16x8*)(&sV[cur][row * 64 + (((4 + lg) ^ (row & 7)) * 8)]);
      acc[ni] = __builtin_amdgcn_mfma_f32_16x16x32_bf16(vf0, pb[0], acc[ni], 0, 0, 0);
      acc[ni] = __builtin_amdgcn_mfma_f32_16x16x32_bf16(vf1, pb[1], acc[ni], 0, 0, 0);
    }

    __syncthreads();
    cur ^= 1;
  }

  // epilogue: normalize, write bf16 Ao (no cross-lane reduction needed)
  const int b = bh >> 4, h = bh & 15;
  const float inv = 1.0f / lacc[0];
  const size_t rowb = ((size_t)(b * SQ + q0 + li)) * DM + h * HD;
#pragma unroll
  for (int ni = 0; ni < 4; ++ni) {
    union { __bf16 h2[4]; uint2 u; } ov;
#pragma unroll
    for (int r = 0; r < 4; ++r) ov.h2[r] = (__bf16)(acc[ni][r] * inv);
    *(uint2*)(Ao + rowb + ni * 16 + lg * 4) = ov.u;
  }
}

extern "C" void kernel_launch(void* const* d_in, const int* in_sizes, int n_in,
                              void* d_out, int out_size, void* d_ws, size_t ws_size,
                              hipStream_t stream) {
  const float* X  = (const float*)d_in[0];
  const float* Wq = (const float*)d_in[1];
  const float* bq = (const float*)d_in[2];
  const float* Wk = (const float*)d_in[3];
  const float* bk = (const float*)d_in[4];
  const float* Wv = (const float*)d_in[5];
  const float* bv = (const float*)d_in[6];
  const float* Wo = (const float*)d_in[7];
  const float* bo = (const float*)d_in[8];
  const int* vlen = (const int*)d_in[9];

  char* ws = (char*)d_ws;
  u16* Qb  = (u16*)(ws);                       // 8 MB [32][2048][64]
  u16* Kb  = (u16*)(ws + (size_t)8388608);     // 8 MB
  u16* Vt  = (u16*)(ws + (size_t)16777216);    // 8 MB [32][64][2048]
  u16* Xb  = (u16*)(ws + (size_t)25165824);    // 8 MB [4096][1024] bf16
  u16* Ao  = Xb;                               // alias: Xb dead after qkv_gemm
  u16* Wqb = (u16*)(ws + (size_t)33554432);    // 2 MB each; Wq/Wk/Wv contiguous
  u16* Wkb = (u16*)(ws + (size_t)35651584);
  u16* Wvb = (u16*)(ws + (size_t)37748736);
  u16* Wob = (u16*)(ws + (size_t)39845888);    // ends at 40 MB

  dim3 blk(256);
  conv_bf16<<<4096, blk, 0, stream>>>(X, Wq, Wk, Wv, Wo, Xb, Wqb, Wkb, Wvb, Wob);
  qkv_gemm<<<dim3(24, 32), blk, 0, stream>>>(Xb, Wqb, bq, bk, bv, Qb, Kb, Vt);
  attn_v9<<<dim3(32, 32), blk, 0, stream>>>(Qb, Kb, Vt, vlen, Ao);
  out_gemm<<<dim3(8, 64), blk, 0, stream>>>(Ao, Wob, bo, (float*)d_out);
}

// Round 11
// 119.104 us; speedup vs baseline: 1.0316x; 1.0316x over previous
//
#include <hip/hip_runtime.h>

#define SQ 2048
#define DM 1024
#define NH 16
#define HD 64

typedef __bf16 bf16x8 __attribute__((ext_vector_type(8)));
typedef float f32x4 __attribute__((ext_vector_type(4)));
typedef unsigned short u16;
typedef unsigned int u32;

// fp32 -> bf16 round-to-nearest-even (bulk convert pass)
__device__ __forceinline__ u16 f2b(float f) {
  union { float f; u32 u; } c; c.f = f;
  return (u16)((c.u + 0x7FFFu + ((c.u >> 16) & 1u)) >> 16);
}

// async global->LDS, 16B per lane; lds dest = wave-uniform base + lane*16
__device__ __forceinline__ void gll16(const void* g, void* l) {
  __builtin_amdgcn_global_load_lds(
      (const __attribute__((address_space(1))) void*)g,
      (__attribute__((address_space(3))) void*)l, 16, 0, 0);
}

// ---------------------------------------------------------------------------
// fp32 -> bf16 convert pass: X (4M elems) + Wq/Wk/Wv/Wo (1M each)
// Wq/Wk/Wv land contiguous -> usable as one 3072x1024 matrix.
// ---------------------------------------------------------------------------
__global__ void __launch_bounds__(256) conv_bf16(
    const float* __restrict__ X,
    const float* __restrict__ Wq, const float* __restrict__ Wk,
    const float* __restrict__ Wv, const float* __restrict__ Wo,
    u16* __restrict__ Xb, u16* __restrict__ Wqb, u16* __restrict__ Wkb,
    u16* __restrict__ Wvb, u16* __restrict__ Wob) {
  const size_t e = ((size_t)blockIdx.x * 256 + threadIdx.x) * 8;
  const float* src; u16* dst; size_t rel;
  if (e < 4194304u)      { src = X;  dst = Xb;  rel = e; }
  else if (e < 5242880u) { src = Wq; dst = Wqb; rel = e - 4194304u; }
  else if (e < 6291456u) { src = Wk; dst = Wkb; rel = e - 5242880u; }
  else if (e < 7340032u) { src = Wv; dst = Wvb; rel = e - 6291456u; }
  else                   { src = Wo; dst = Wob; rel = e - 7340032u; }
  float4 a = *(const float4*)(src + rel);
  float4 b = *(const float4*)(src + rel + 4);
  union { u16 h[8]; uint4 v; } o;
  o.h[0] = f2b(a.x); o.h[1] = f2b(a.y); o.h[2] = f2b(a.z); o.h[3] = f2b(a.w);
  o.h[4] = f2b(b.x); o.h[5] = f2b(b.y); o.h[6] = f2b(b.z); o.h[7] = f2b(b.w);
  *(uint4*)(dst + rel) = o.v;
}

// ---------------------------------------------------------------------------
// m97-style 128x128 NT GEMM core, bf16 inputs, BK=32, global_load_lds staging,
// double-buffered LDS ([2][128][32] linear per operand), 2-phase schedule.
// ---------------------------------------------------------------------------
__device__ __forceinline__ void stage128(const u16* __restrict__ A, const u16* __restrict__ B,
                                         u16* sA, u16* sB, int m0, int n0, int kt,
                                         int w, int l) {
#pragma unroll
  for (int c = 0; c < 2; ++c) {
    const int g = w * 2 + c;       // chunk-group 0..7 (1 KB each)
    const int s = g * 64 + l;      // 16B slot 0..511
    const int r = s >> 2, cc = s & 3;
    gll16(A + (size_t)(m0 + r) * DM + kt * 32 + cc * 8, sA + g * 512);
    gll16(B + (size_t)(n0 + r) * DM + kt * 32 + cc * 8, sB + g * 512);
  }
}

__device__ __forceinline__ void gemm_core2(const u16* __restrict__ A, const u16* __restrict__ B,
                                           u16* sA, u16* sB,   // each [2][4096] u16
                                           int m0, int n0, f32x4 acc[4][4]) {
  const int t = threadIdx.x, l = t & 63, w = t >> 6;
  const int wr = w >> 1, wc = w & 1, lg = l >> 4, li = l & 15;

  stage128(A, B, sA, sB, m0, n0, 0, w, l);
  __syncthreads();  // drains vmcnt(0) before barrier
  int cur = 0;
  for (int kt = 0; kt < DM / 32; ++kt) {
    if (kt + 1 < DM / 32)
      stage128(A, B, sA + (cur ^ 1) * 4096, sB + (cur ^ 1) * 4096, m0, n0, kt + 1, w, l);
    bf16x8 aF[4], bF[4];
#pragma unroll
    for (int mi = 0; mi < 4; ++mi)
      aF[mi] = *(const bf16x8*)(sA + cur * 4096 + (wr * 64 + mi * 16 + li) * 32 + lg * 8);
#pragma unroll
    for (int ni = 0; ni < 4; ++ni)
      bF[ni] = *(const bf16x8*)(sB + cur * 4096 + (wc * 64 + ni * 16 + li) * 32 + lg * 8);
#pragma unroll
    for (int mi = 0; mi < 4; ++mi)
#pragma unroll
      for (int ni = 0; ni < 4; ++ni)
        acc[mi][ni] = __builtin_amdgcn_mfma_f32_16x16x32_bf16(aF[mi], bF[ni], acc[mi][ni], 0, 0, 0);
    __syncthreads();
    cur ^= 1;
  }
}

// ---------------------------------------------------------------------------
// Merged QKV projection: one 4096x3072x1024 GEMM (Wqkv contiguous bf16).
// n in [0,1024): Q (scaled log2e/8); [1024,2048): K; [2048,3072): V^T.
// ---------------------------------------------------------------------------
__global__ void __launch_bounds__(256) qkv_gemm(
    const u16* __restrict__ Xb, const u16* __restrict__ Wqkv,
    const float* __restrict__ bq, const float* __restrict__ bk, const float* __restrict__ bv,
    u16* __restrict__ Qb, u16* __restrict__ Kb, u16* __restrict__ Vt) {
  __shared__ u16 sA[8192];
  __shared__ u16 sB[8192];
  const int m0 = blockIdx.y * 128, n0 = blockIdx.x * 128;
  const int mode = n0 >> 10;              // 0:Q 1:K 2:V (block-uniform)
  const float* bias = (mode == 0) ? bq : (mode == 1) ? bk : bv;

  f32x4 acc[4][4];
  f32x4 z4 = {0.f, 0.f, 0.f, 0.f};
#pragma unroll
  for (int i = 0; i < 4; ++i)
#pragma unroll
    for (int j = 0; j < 4; ++j) acc[i][j] = z4;

  gemm_core2(Xb, Wqkv, sA, sB, m0, n0, acc);

  const int t = threadIdx.x;
  const int l = t & 63, w = t >> 6;
  const int wr = w >> 1, wc = w & 1, lg = l >> 4, li = l & 15;
#pragma unroll
  for (int mi = 0; mi < 4; ++mi) {
    const int m = m0 + wr * 64 + mi * 16 + lg * 4;
    const int b = m >> 11;           // batch
    const int s = m & 2047;          // seq pos
#pragma unroll
    for (int ni = 0; ni < 4; ++ni) {
      const int n = n0 + wc * 64 + ni * 16 + li;
      const int nn = n - (mode << 10);     // local col 0..1023
      const int h = nn >> 6, dd = nn & 63;
      const float bia = bias[nn];
      const size_t bh = (size_t)(b * NH + h);
      if (mode == 2) {
        // V^T: 4 consecutive seq positions for fixed dd -> one 8B store
        union { u16 h4[4]; uint2 u; } pk;
#pragma unroll
        for (int r = 0; r < 4; ++r) pk.h4[r] = f2b(acc[mi][ni][r] + bia);
        *(uint2*)(Vt + (bh * HD + dd) * SQ + s) = pk.u;
      } else {
#pragma unroll
        for (int r = 0; r < 4; ++r) {
          const float val = acc[mi][ni][r] + bia;
          const int ss = s + r;
          // Q prescale: (1/sqrt(HD)) * log2(e) so attn works in exp2 domain
          if (mode == 0) Qb[(bh * SQ + ss) * HD + dd] = f2b(val * 0.180336880f);
          else           Kb[(bh * SQ + ss) * HD + dd] = f2b(val);
        }
      }
    }
  }
}

// ---------------------------------------------------------------------------
// Final projection: out = Ao * Wo^T + bo (bf16 in, fp32 out).
// 64x128 tile, grid (8,64) = 512 blocks = 2 blocks/CU.
// ---------------------------------------------------------------------------
__global__ void __launch_bounds__(256) out_gemm(
    const u16* __restrict__ Ag, const u16* __restrict__ Wob,
    const float* __restrict__ bo, float* __restrict__ out) {
  __shared__ u16 sA[2][2048];   // [64][32] u16 per buf (4KB)
  __shared__ u16 sB[2][4096];   // [128][32] u16 per buf (8KB)
  const int t = threadIdx.x, l = t & 63, w = t >> 6;
  const int wr = w >> 1, wc = w & 1, lg = l >> 4, li = l & 15;
  const int m0 = blockIdx.y * 64, n0 = blockIdx.x * 128;

  auto stage = [&](int buf, int kt) {
    {
      const int s = w * 64 + l;          // A slot 0..255
      const int r = s >> 2, cc = s & 3;
      gll16(Ag + (size_t)(m0 + r) * DM + kt * 32 + cc * 8, &sA[buf][w * 512]);
    }
#pragma unroll
    for (int c = 0; c < 2; ++c) {
      const int g = w * 2 + c;           // B chunk 0..7
      const int s = g * 64 + l;          // B slot 0..511
      const int r = s >> 2, cc = s & 3;
      gll16(Wob + (size_t)(n0 + r) * DM + kt * 32 + cc * 8, &sB[buf][g * 512]);
    }
  };

  f32x4 acc[2][4];
  f32x4 z4 = {0.f, 0.f, 0.f, 0.f};
#pragma unroll
  for (int i = 0; i < 2; ++i)
#pragma unroll
    for (int j = 0; j < 4; ++j) acc[i][j] = z4;

  stage(0, 0);
  __syncthreads();
  int cur = 0;
  for (int kt = 0; kt < DM / 32; ++kt) {
    if (kt + 1 < DM / 32) stage(cur ^ 1, kt + 1);
    bf16x8 aF[2], bF[4];
#pragma unroll
    for (int mi = 0; mi < 2; ++mi)
      aF[mi] = *(const bf16x8*)(&sA[cur][(wr * 32 + mi * 16 + li) * 32 + lg * 8]);
#pragma unroll
    for (int ni = 0; ni < 4; ++ni)
      bF[ni] = *(const bf16x8*)(&sB[cur][(wc * 64 + ni * 16 + li) * 32 + lg * 8]);
#pragma unroll
    for (int mi = 0; mi < 2; ++mi)
#pragma unroll
      for (int ni = 0; ni < 4; ++ni)
        acc[mi][ni] = __builtin_amdgcn_mfma_f32_16x16x32_bf16(aF[mi], bF[ni], acc[mi][ni], 0, 0, 0);
    __syncthreads();
    cur ^= 1;
  }

#pragma unroll
  for (int mi = 0; mi < 2; ++mi) {
    const int m = m0 + wr * 32 + mi * 16 + lg * 4;
#pragma unroll
    for (int ni = 0; ni < 4; ++ni) {
      const int n = n0 + wc * 64 + ni * 16 + li;
      const float bia = bo[n];
#pragma unroll
      for (int r = 0; r < 4; ++r)
        out[(size_t)(m + r) * DM + n] = acc[mi][ni][r] + bia;
    }
  }
}

// ---------------------------------------------------------------------------
// Flash attention v10: R=1 key-split, barrier-free main loop.
//  - block = 64 queries; each wave computes ALL 64 q over a PRIVATE 512-key
//    range (16 tiles of 32 keys), staged into its own dbuf LDS (2x8KB).
//    Fixed-anchor softmax (p = exp2(sc)) makes O/l partials additive across
//    key ranges -> single cross-wave LDS reduction at the end.
//  - no __syncthreads in the loop: per-wave counted s_waitcnt vmcnt(8)
//    (8 gll16/tile in flight for t+1 while t is consumed)   [T3/T4 pattern]
//  - sigma-permuted K rows (sig = lg*8+ni*4+r) -> zero-shuffle P->PV
//  - LDS reads per wave-tile: 8 KB for 36 MFMA (4x less traffic than v9)
//  - masked queries via qf=0; l via ones-MFMA; bh-fastest grid (XCD pinning)
// ---------------------------------------------------------------------------
__global__ void __launch_bounds__(256, 2) attn_v10(
    const u16* __restrict__ Qb, const u16* __restrict__ Kb, const u16* __restrict__ Vt,
    const int* __restrict__ vlen, u16* __restrict__ Ao) {
  __shared__ u16 sKV[4][2][4096];   // [wave][buf][ K[32][64] | V^T[64][32] ]
  __shared__ float lpart[4][4][16]; // [wave][group][q-lane]
  const int bh = blockIdx.x, qt = blockIdx.y;
  const int t = threadIdx.x, w = t >> 6, l = t & 63, lg = l >> 4, li = l & 15;
  const int vl = vlen[bh];
  const u16* Qh = Qb + (size_t)bh * SQ * HD;
  const u16* Kh = Kb + (size_t)bh * SQ * HD;
  const u16* Vh = Vt + (size_t)bh * HD * SQ;
  const int q0 = qt * 64;            // block's 64 queries; group g: q0+g*16+li
  const int k0 = w * 512;            // wave's private key range

  // Q fragments for 4 groups, masked queries zeroed
  bf16x8 qf[4][2];
#pragma unroll
  for (int g = 0; g < 4; ++g) {
    const bool mq = (q0 + g * 16 + li) >= vl;
#pragma unroll
    for (int kk = 0; kk < 2; ++kk) {
      qf[g][kk] = *(const bf16x8*)(Qh + (size_t)(q0 + g * 16 + li) * HD + kk * 32 + lg * 8);
      if (mq) {
        union { u32 u[4]; bf16x8 v; } z; z.u[0] = z.u[1] = z.u[2] = z.u[3] = 0;
        qf[g][kk] = z.v;
      }
    }
  }

  // ones A-fragment (for l = ones * P MFMA)
  union { u16 h[8]; bf16x8 v; } onesU;
#pragma unroll
  for (int j = 0; j < 8; ++j) onesU.h[j] = 0x3F80;  // bf16 1.0
  const bf16x8 ones = onesU.v;

  // staging offsets (loop-invariant). K: 4 instrs cover [32 rows][8 slots];
  // sigma row permute + XOR slot swizzle folded into the global source addr.
  // V: 4 instrs cover [64 d][4 slots]; XOR-4 swizzle.
  int kOff[4], vOff[4];
#pragma unroll
  for (int i = 0; i < 4; ++i) {
    {
      const int s = i * 64 + l, row = s >> 3, c = s & 7;
      const int csrc = c ^ (row & 7);
      const int sig = (((row >> 2) & 3) << 3) | (((row >> 4) & 1) << 2) | (row & 3);
      kOff[i] = sig * HD + csrc * 8;
    }
    {
      const int s = i * 64 + l, d = s >> 2, c = s & 3;
      const int csrc = c ^ (d & 3);
      vOff[i] = d * SQ + csrc * 8;
    }
  }

  u16* sw = &sKV[w][0][0];   // this wave's 16KB (bufs at +0 / +4096)
  auto stage = [&](int buf, int tt) {
    const u16* kb = Kh + (size_t)(k0 + tt * 32) * HD;
    const u16* vb = Vh + (size_t)(k0 + tt * 32);
    u16* db = sw + buf * 4096;
#pragma unroll
    for (int i = 0; i < 4; ++i) gll16(kb + kOff[i], db + i * 512);
#pragma unroll
    for (int i = 0; i < 4; ++i) gll16(vb + vOff[i], db + 2048 + i * 512);
  };

  f32x4 z4 = {0.f, 0.f, 0.f, 0.f};
  f32x4 acc[4][4], lacc[4];
#pragma unroll
  for (int g = 0; g < 4; ++g) {
    lacc[g] = z4;
#pragma unroll
    for (int n2 = 0; n2 < 4; ++n2) acc[g][n2] = z4;
  }

  stage(0, 0);
  int cur = 0;
  for (int tt = 0; tt < 16; ++tt) {
    if (tt < 15) {
      stage(cur ^ 1, tt + 1);
      asm volatile("s_waitcnt vmcnt(8)" ::: "memory");  // tile tt landed; tt+1 in flight
    } else {
      asm volatile("s_waitcnt vmcnt(0)" ::: "memory");
    }
    const u16* kb_ = sw + cur * 4096;          // K [32 rows(sigma)][64 dk]
    const u16* vb_ = sw + cur * 4096 + 2048;   // V^T [64 d][32 k]

    // shared K/V fragments (read once, used by all 4 groups)
    bf16x8 kf[2][2], vf[4];
#pragma unroll
    for (int ni = 0; ni < 2; ++ni) {
      const int row = ni * 16 + li;
      kf[ni][0] = *(const bf16x8*)(kb_ + row * 64 + ((lg ^ (row & 7)) * 8));
      kf[ni][1] = *(const bf16x8*)(kb_ + row * 64 + (((4 + lg) ^ (row & 7)) * 8));
    }
#pragma unroll
    for (int n2 = 0; n2 < 4; ++n2) {
      const int d = n2 * 16 + li;
      vf[n2] = *(const bf16x8*)(vb_ + d * 32 + ((lg ^ (d & 3)) * 8));
    }

#pragma unroll
    for (int g = 0; g < 4; ++g) {
      // S^T = K Q^T (log2 domain), 32 keys x 16 q
      f32x4 s0 = __builtin_amdgcn_mfma_f32_16x16x32_bf16(kf[0][0], qf[g][0], z4, 0, 0, 0);
      s0 = __builtin_amdgcn_mfma_f32_16x16x32_bf16(kf[0][1], qf[g][1], s0, 0, 0, 0);
      f32x4 s1 = __builtin_amdgcn_mfma_f32_16x16x32_bf16(kf[1][0], qf[g][0], z4, 0, 0, 0);
      s1 = __builtin_amdgcn_mfma_f32_16x16x32_bf16(kf[1][1], qf[g][1], s1, 0, 0, 0);

      // fixed-anchor softmax, packed straight into the PV B-frag
      union { __bf16 e[8]; bf16x8 v; } P;
#pragma unroll
      for (int r = 0; r < 4; ++r) {
        P.e[r]     = (__bf16)__builtin_amdgcn_exp2f(s0[r]);
        P.e[4 + r] = (__bf16)__builtin_amdgcn_exp2f(s1[r]);
      }

      lacc[g] = __builtin_amdgcn_mfma_f32_16x16x32_bf16(ones, P.v, lacc[g], 0, 0, 0);
#pragma unroll
      for (int n2 = 0; n2 < 4; ++n2)
        acc[g][n2] = __builtin_amdgcn_mfma_f32_16x16x32_bf16(vf[n2], P.v, acc[g][n2], 0, 0, 0);
    }
    cur ^= 1;
  }

  // ---- cross-wave reduction (O and l partials are additive) ----
  __syncthreads();                      // all waves done with their LDS bufs
  f32x4* op = (f32x4*)&sKV[0][0][0];    // reuse as [wave][group][n2][lane] f32x4
#pragma unroll
  for (int g = 0; g < 4; ++g) {
#pragma unroll
    for (int n2 = 0; n2 < 4; ++n2)
      op[(((w * 4) + g) * 4 + n2) * 64 + l] = acc[g][n2];
    if (lg == 0) lpart[w][g][li] = lacc[g][0];
  }
  __syncthreads();

  // wave w reduces + writes group g = w (queries q0 + w*16 + li)
  const int g = w;
  const float lf = lpart[0][g][li] + lpart[1][g][li] + lpart[2][g][li] + lpart[3][g][li];
  const float inv = 1.0f / lf;
  const int b = bh >> 4, h = bh & 15;
  const size_t rowb = ((size_t)(b * SQ + q0 + g * 16 + li)) * DM + h * HD;
#pragma unroll
  for (int n2 = 0; n2 < 4; ++n2) {
    f32x4 s = op[((0 * 4 + g) * 4 + n2) * 64 + l];
    s += op[((1 * 4 + g) * 4 + n2) * 64 + l];
    s += op[((2 * 4 + g) * 4 + n2) * 64 + l];
    s += op[((3 * 4 + g) * 4 + n2) * 64 + l];
    union { __bf16 h2[4]; uint2 u; } ov;
#pragma unroll
    for (int r = 0; r < 4; ++r) ov.h2[r] = (__bf16)(s[r] * inv);
    *(uint2*)(Ao + rowb + n2 * 16 + lg * 4) = ov.u;
  }
}

extern "C" void kernel_launch(void* const* d_in, const int* in_sizes, int n_in,
                              void* d_out, int out_size, void* d_ws, size_t ws_size,
                              hipStream_t stream) {
  const float* X  = (const float*)d_in[0];
  const float* Wq = (const float*)d_in[1];
  const float* bq = (const float*)d_in[2];
  const float* Wk = (const float*)d_in[3];
  const float* bk = (const float*)d_in[4];
  const float* Wv = (const float*)d_in[5];
  const float* bv = (const float*)d_in[6];
  const float* Wo = (const float*)d_in[7];
  const float* bo = (const float*)d_in[8];
  const int* vlen = (const int*)d_in[9];

  char* ws = (char*)d_ws;
  u16* Qb  = (u16*)(ws);                       // 8 MB [32][2048][64]
  u16* Kb  = (u16*)(ws + (size_t)8388608);     // 8 MB
  u16* Vt  = (u16*)(ws + (size_t)16777216);    // 8 MB [32][64][2048]
  u16* Xb  = (u16*)(ws + (size_t)25165824);    // 8 MB [4096][1024] bf16
  u16* Ao  = Xb;                               // alias: Xb dead after qkv_gemm
  u16* Wqb = (u16*)(ws + (size_t)33554432);    // 2 MB each; Wq/Wk/Wv contiguous
  u16* Wkb = (u16*)(ws + (size_t)35651584);
  u16* Wvb = (u16*)(ws + (size_t)37748736);
  u16* Wob = (u16*)(ws + (size_t)39845888);    // ends at 40 MB

  dim3 blk(256);
  conv_bf16<<<4096, blk, 0, stream>>>(X, Wq, Wk, Wv, Wo, Xb, Wqb, Wkb, Wvb, Wob);
  qkv_gemm<<<dim3(24, 32), blk, 0, stream>>>(Xb, Wqb, bq, bk, bv, Qb, Kb, Vt);
  attn_v10<<<dim3(32, 32), blk, 0, stream>>>(Qb, Kb, Vt, vlen, Ao);
  out_gemm<<<dim3(8, 64), blk, 0, stream>>>(Ao, Wob, bo, (float*)d_out);
}